// Round 8
// baseline (1159.042 us; speedup 1.0000x reference)
//
#include <hip/hip_runtime.h>
#include <stdint.h>

#define K_DIM 4096
#define N_DIM 11008
#define M_DIM 8192
#define BM 256
#define BN 256
#define BK 64
#define NSLAB (K_DIM / BK)   // 64
#define NBN (N_DIM / BN)     // 43
#define NBM (M_DIM / BM)     // 32
#define NWG (NBN * NBM)      // 1376, % 8 == 0
#define ABUF (BM * BK)       // 16384 halves = 32 KiB
#define BBUF (BN * BK)       // 16384 halves = 32 KiB

// fallback (round-0 validated) kernel params
#define FBM 128
#define FBK 32
#define FASTRIDE 32
#define FBSTRIDE 40

typedef _Float16 half8   __attribute__((ext_vector_type(8)));
typedef _Float16 half2v  __attribute__((ext_vector_type(2)));
typedef float    floatx4 __attribute__((ext_vector_type(4)));

#define WS_NEEDED ((size_t)M_DIM * K_DIM * 2)   // 64 MiB: fp16 copy of x

__device__ __forceinline__ void async_lds16(const void* g, void* l) {
    __builtin_amdgcn_global_load_lds(
        (const __attribute__((address_space(1))) uint32_t*)g,
        (__attribute__((address_space(3))) uint32_t*)l, 16, 0, 0);
}

// ---------------- prepass: x fp32 -> fp16 (lossless; values are fp16-representable) ----
__global__ __launch_bounds__(256) void cvt_a(const float* __restrict__ x,
                                             _Float16* __restrict__ xh) {
    const size_t i = ((size_t)blockIdx.x * 256 + threadIdx.x) * 8;
    const float4 a = *(const float4*)(x + i);
    const float4 b = *(const float4*)(x + i + 4);
    half8 h;
    h[0] = (_Float16)a.x; h[1] = (_Float16)a.y; h[2] = (_Float16)a.z; h[3] = (_Float16)a.w;
    h[4] = (_Float16)b.x; h[5] = (_Float16)b.y; h[6] = (_Float16)b.z; h[7] = (_Float16)b.w;
    *(half8*)(xh + i) = h;
}

// ---------------- main GEMM: 256x256, ALL double-buffered, ONE barrier per slab --------
// A: dbuf via global_load_lds (counted vmcnt(3): A-DMA(t+1) drained at barrier, pv(t+2)
//    stays in flight).  B: dbuf via in-register dequant + swizzled ds_write -- dequant of
//    slab t+1 is INDEPENDENT of MFMA(t), so the scheduler interleaves the ~360 VALU ops
//    under the 64-MFMA cluster (this was the serialized 40% in r2..r7).  Zero-conflict
//    XOR chunk swizzle both sides (r3/r4-proven).  1 block/CU (128 KiB LDS), 8 waves.
__global__ __launch_bounds__(512, 2) void ternary_gemm_u1(
    const _Float16* __restrict__ xh,   // (M, K) fp16
    const int*   __restrict__ pw,      // (K/16, N) packed 2-bit codes
    const float* __restrict__ scales,  // (K/128, N) fp32 holding fp16 values
    const float* __restrict__ bias,    // (N,) fp32 holding fp16 values
    float*       __restrict__ out)     // (M, N) fp32
{
    __shared__ __align__(16) _Float16 lds_a[2 * ABUF];  // 64 KiB
    __shared__ __align__(16) _Float16 lds_b[2 * BBUF];  // 64 KiB

    const int tid  = threadIdx.x;
    const int lane = tid & 63;
    const int w    = tid >> 6;

    // XCD-aware bijective swizzle, m-panel-major (XCD chunk = 172 = 4 m-panels x 43)
    const int bid = blockIdx.x;
    const int swz = (bid & 7) * (NWG / 8) + (bid >> 3);
    const int m0 = (swz / NBN) * BM;
    const int n0 = (swz % NBN) * BN;

    const int wm = (w >> 2) * 128;   // 8 waves = 2m x 4n; wave tile 128x64
    const int wn = (w & 3) * 64;

    // ---- A staging: 4 x 16B DMA per thread; linear LDS dest, pre-swizzled source ----
    const _Float16* ga[4];
    int laOff[4];
    #pragma unroll
    for (int i = 0; i < 4; ++i) {
        const int idx = tid + i * 512;          // 0..2047
        const int row = idx >> 3;               // 0..255
        const int c   = idx & 7;
        ga[i]    = xh + (size_t)(m0 + row) * K_DIM + ((c ^ (row & 7)) * 8);
        laOff[i] = idx * 8;
    }

    // ---- B staging: thread = (col nb, dword pair kp); 2 dwords -> 4 swizzled chunks ----
    const int nb = tid >> 1;                    // 0..255
    const int kp = tid & 1;                     // dwords kp*2, kp*2+1 within slab
    const int* pwp = pw + (size_t)(kp * 2) * N_DIM + n0 + nb;
    const float* scp = scales + n0 + nb;
    const int s7  = nb & 7;
    const int c0a = (kp * 4 + 0) ^ s7;
    const int c0b = (kp * 4 + 1) ^ s7;
    const int c1a = (kp * 4 + 2) ^ s7;
    const int c1b = (kp * 4 + 3) ^ s7;
    const int blOff = nb * BK;

    floatx4 acc[8][4];
    #pragma unroll
    for (int i = 0; i < 8; ++i)
        #pragma unroll
        for (int j = 0; j < 4; ++j)
            acc[i][j] = floatx4{0.f, 0.f, 0.f, 0.f};

    const int lr = lane & 15;                   // row (A) / col (B,C) within 16-tile
    const int g  = lane >> 4;                   // k-quad
    const int x7 = lr & 7;

    int aoff[8], boff[4];
    #pragma unroll
    for (int t = 0; t < 8; ++t) aoff[t] = (wm + t * 16 + lr) * BK;
    #pragma unroll
    for (int t = 0; t < 4; ++t) boff[t] = (wn + t * 16 + lr) * BK;

    auto stage_a = [&](int t, int buf) {
        #pragma unroll
        for (int i = 0; i < 4; ++i)
            async_lds16(ga[i] + t * BK, lds_a + buf * ABUF + laOff[i]);
    };
    auto permq = [](uint32_t v, uint32_t tmpl, uint32_t* q) {
        #pragma unroll
        for (int j = 0; j < 8; ++j) {
            uint32_t t4 = (v >> (4 * j)) & 0xFu;             // c0 @bits1:0, c1 @bits3:2
            uint32_t sp = (t4 | (t4 << 14)) & 0x00030003u;   // c0 @byte0, c1 @byte2
            uint32_t sel = ((sp & 0x00010001u) << 1) | ((0x00030003u - sp) << 8);
            q[j] = __builtin_amdgcn_perm(tmpl, tmpl, sel);
        }
    };
    // exact ternary dequant: 32 codes -> fp16 {-s, 0, +s} via v_perm byte templates
    auto stage_b = [&](uint32_t v0, uint32_t v1, float scf, int buf) {
        _Float16* rowb = lds_b + buf * BBUF + blOff;
        _Float16 sh = (_Float16)scf;            // lossless (value is fp16)
        uint32_t sbits = (uint32_t)__builtin_bit_cast(unsigned short, sh);
        // template bytes: [0]=lo(s) [1]=hi(+s) [2]=0x00 [3]=hi(-s); s > 0
        uint32_t tmpl = sbits | (((sbits >> 8) ^ 0x80u) << 24);
        uint32_t q[8];
        permq(v0, tmpl, q);
        *(uint4*)(rowb + c0a * 8) = make_uint4(q[0], q[1], q[2], q[3]);
        *(uint4*)(rowb + c0b * 8) = make_uint4(q[4], q[5], q[6], q[7]);
        permq(v1, tmpl, q);
        *(uint4*)(rowb + c1a * 8) = make_uint4(q[0], q[1], q[2], q[3]);
        *(uint4*)(rowb + c1b * 8) = make_uint4(q[4], q[5], q[6], q[7]);
    };

    // ---- prologue: B(0) dequant -> buf0, A(0) DMA -> buf0, pv(1) in regs; full drain ----
    {
        uint32_t p0 = (uint32_t)pwp[0];
        uint32_t p1 = (uint32_t)pwp[(size_t)1 * N_DIM];
        float    s0 = scp[0];
        stage_a(0, 0);
        stage_b(p0, p1, s0, 0);
    }
    uint32_t pvA0 = (uint32_t)pwp[(size_t)4 * N_DIM];   // slab 1 operands
    uint32_t pvA1 = (uint32_t)pwp[(size_t)5 * N_DIM];
    float    svA  = scp[0];                             // group of slab 1 == 0
    asm volatile("s_waitcnt vmcnt(0) lgkmcnt(0)" ::: "memory");
    __builtin_amdgcn_s_barrier();

    for (int t = 0; t < NSLAB; ++t) {
        const int cur = t & 1;
        const _Float16* Ab = lds_a + cur * ABUF;
        const _Float16* Bb = lds_b + cur * BBUF;

        // (a) next slab's A-DMA into the other buffer
        if (t + 1 < NSLAB) stage_a(t + 1, cur ^ 1);
        // (b) prefetch slab t+2's packed dwords + scale (stay in flight across barrier)
        uint32_t pvB0 = 0, pvB1 = 0; float svB = 0.f;
        if (t + 2 < NSLAB) {
            pvB0 = (uint32_t)pwp[(size_t)((t + 2) * 4 + 0) * N_DIM];
            pvB1 = (uint32_t)pwp[(size_t)((t + 2) * 4 + 1) * N_DIM];
            svB  = scp[(size_t)((t + 2) >> 1) * N_DIM];
        }
        // (c) dequant B(t+1) -> other buffer: INDEPENDENT of MFMA(t) -> interleaved
        if (t + 1 < NSLAB) stage_b(pvA0, pvA1, svA, cur ^ 1);

        // (d) MFMA on buf[cur] (r6's zero-conflict fragment pattern, 128x64 wave tile)
        #pragma unroll
        for (int h = 0; h < 2; ++h) {
            const int co = ((h * 4 + g) ^ x7) * 8;
            half8 af[8], bfr[4];
            #pragma unroll
            for (int tt = 0; tt < 8; ++tt) af[tt]  = *(const half8*)&Ab[aoff[tt] + co];
            #pragma unroll
            for (int tt = 0; tt < 4; ++tt) bfr[tt] = *(const half8*)&Bb[boff[tt] + co];
            #pragma unroll
            for (int mt = 0; mt < 8; ++mt)
                #pragma unroll
                for (int nt = 0; nt < 4; ++nt)
                    acc[mt][nt] = __builtin_amdgcn_mfma_f32_16x16x32_f16(
                        af[mt], bfr[nt], acc[mt][nt], 0, 0, 0);
        }

        // (e) single publish barrier: A-DMA(t+1) drained (vmcnt(3): pv(t+2) in flight),
        //     B(t+1) writes + my frag reads drained (lgkm 0)
        if (t + 2 < NSLAB) asm volatile("s_waitcnt vmcnt(3)" ::: "memory");
        else               asm volatile("s_waitcnt vmcnt(0)" ::: "memory");
        asm volatile("s_waitcnt lgkmcnt(0)" ::: "memory");
        __builtin_amdgcn_sched_barrier(0);
        __builtin_amdgcn_s_barrier();

        pvA0 = pvB0; pvA1 = pvB1; svA = svB;
    }

    // ---- epilogue: fp32 acc + fp32 bias, stored unrounded (validated numerics) ----
    float bv[4];
    #pragma unroll
    for (int nt = 0; nt < 4; ++nt) bv[nt] = bias[n0 + wn + nt * 16 + lr];

    const int rbase = g * 4;          // C layout: row = (lane>>4)*4 + reg
    #pragma unroll
    for (int mt = 0; mt < 8; ++mt) {
        #pragma unroll
        for (int nt = 0; nt < 4; ++nt) {
            const int col = n0 + wn + nt * 16 + lr;
            float* op = out + (size_t)(m0 + wm + mt * 16 + rbase) * N_DIM + col;
            floatx4 a = acc[mt][nt];
            #pragma unroll
            for (int r = 0; r < 4; ++r)
                op[(size_t)r * N_DIM] = a[r] + bv[nt];
        }
    }
}

// ---------------- fallback: round-0 validated kernel (used if ws too small) ------------
__global__ __launch_bounds__(256, 2) void ternary_gemm(
    const float* __restrict__ x,
    const int*   __restrict__ pw,
    const float* __restrict__ scales,
    const float* __restrict__ bias,
    float*       __restrict__ out)
{
    __shared__ __align__(16) _Float16 lds_a[FBM * FASTRIDE];
    __shared__ __align__(16) _Float16 lds_b[FBM * FBSTRIDE];

    const int tid  = threadIdx.x;
    const int lane = tid & 63;
    const int wave = tid >> 6;

    const int n0 = blockIdx.x * FBM;
    const int m0 = blockIdx.y * FBM;

    const int wm = (wave & 1) * 64;
    const int wn = (wave >> 1) * 64;

    const int nb  = tid & 127;
    const int kpi = tid >> 7;
    const int*   pwp = pw + (size_t)kpi * N_DIM + n0 + nb;
    const float* scp = scales + n0 + nb;
    _Float16* bl = lds_b + nb * FBSTRIDE + kpi * 16;

    floatx4 acc[4][4];
    #pragma unroll
    for (int i = 0; i < 4; ++i)
        #pragma unroll
        for (int j = 0; j < 4; ++j)
            acc[i][j] = floatx4{0.f, 0.f, 0.f, 0.f};

    const int lr = lane & 15;
    const int qk = (lane >> 4) * 8;

    for (int slab = 0; slab < K_DIM / FBK; ++slab) {
        const int k0 = slab * FBK;

        #pragma unroll
        for (int i = 0; i < 4; ++i) {
            const int idx = tid + i * 256;
            const int row = idx >> 3;
            const int kq  = (idx & 7) * 4;
            float4 v4 = *(const float4*)(x + (size_t)(m0 + row) * K_DIM + k0 + kq);
            half2v h0; h0[0] = (_Float16)v4.x; h0[1] = (_Float16)v4.y;
            half2v h1; h1[0] = (_Float16)v4.z; h1[1] = (_Float16)v4.w;
            *(uint2*)(lds_a + row * FASTRIDE + kq) =
                make_uint2(__builtin_bit_cast(uint32_t, h0),
                           __builtin_bit_cast(uint32_t, h1));
        }

        uint32_t v  = (uint32_t)pwp[(size_t)slab * 2 * N_DIM];
        _Float16 sh = (_Float16)scp[(size_t)(slab >> 2) * N_DIM];
        uint32_t sbits = (uint32_t)__builtin_bit_cast(unsigned short, sh);
        uint32_t tmpl = sbits | (((sbits >> 8) ^ 0x80u) << 24);

        uint32_t q[8];
        #pragma unroll
        for (int j = 0; j < 8; ++j) {
            uint32_t t4 = (v >> (4 * j)) & 0xFu;
            uint32_t sp = (t4 | (t4 << 14)) & 0x00030003u;
            uint32_t sel = ((sp & 0x00010001u) << 1) | ((0x00030003u - sp) << 8);
            q[j] = __builtin_amdgcn_perm(tmpl, tmpl, sel);
        }
        *(uint4*)(bl)     = make_uint4(q[0], q[1], q[2], q[3]);
        *(uint4*)(bl + 8) = make_uint4(q[4], q[5], q[6], q[7]);

        __syncthreads();

        half8 af[4], bfr[4];
        #pragma unroll
        for (int t = 0; t < 4; ++t) {
            af[t]  = *(const half8*)&lds_a[(wm + t * 16 + lr) * FASTRIDE + qk];
            bfr[t] = *(const half8*)&lds_b[(wn + t * 16 + lr) * FBSTRIDE + qk];
        }
        #pragma unroll
        for (int mt = 0; mt < 4; ++mt)
            #pragma unroll
            for (int nt = 0; nt < 4; ++nt)
                acc[mt][nt] = __builtin_amdgcn_mfma_f32_16x16x32_f16(
                    af[mt], bfr[nt], acc[mt][nt], 0, 0, 0);

        __syncthreads();
    }

    float bv[4];
    #pragma unroll
    for (int nt = 0; nt < 4; ++nt) bv[nt] = bias[n0 + wn + nt * 16 + lr];

    const int rbase = (lane >> 4) * 4;
    #pragma unroll
    for (int mt = 0; mt < 4; ++mt) {
        #pragma unroll
        for (int nt = 0; nt < 4; ++nt) {
            const int col = n0 + wn + nt * 16 + lr;
            float* op = out + (size_t)(m0 + wm + mt * 16 + rbase) * N_DIM + col;
            floatx4 a = acc[mt][nt];
            #pragma unroll
            for (int r = 0; r < 4; ++r)
                op[(size_t)r * N_DIM] = a[r] + bv[nt];
        }
    }
}

extern "C" void kernel_launch(void* const* d_in, const int* in_sizes, int n_in,
                              void* d_out, int out_size, void* d_ws, size_t ws_size,
                              hipStream_t stream) {
    const float* x  = (const float*)d_in[0];
    const int*   pw = (const int*)d_in[1];
    const float* sc = (const float*)d_in[2];
    const float* bs = (const float*)d_in[3];
    float* out = (float*)d_out;

    if (d_ws != nullptr && ws_size >= WS_NEEDED) {
        _Float16* xh = (_Float16*)d_ws;
        cvt_a<<<dim3((unsigned)((size_t)M_DIM * K_DIM / (256 * 8))), 256, 0, stream>>>(x, xh);
        ternary_gemm_u1<<<dim3(NWG), 512, 0, stream>>>(xh, pw, sc, bs, out);
    } else {
        ternary_gemm<<<dim3(N_DIM / FBM, M_DIM / FBM), 256, 0, stream>>>(x, pw, sc, bs, out);
    }
}

// Round 9
// 1145.742 us; speedup vs baseline: 1.0116x; 1.0116x over previous
//
#include <hip/hip_runtime.h>
#include <stdint.h>

#define K_DIM 4096
#define N_DIM 11008
#define M_DIM 8192
#define BM 256
#define BN 128
#define BK 32
#define NSLAB (K_DIM / BK)   // 128
#define NPAIR (NSLAB / 2)    // 64
#define NBN (N_DIM / BN)     // 86
#define NBM (M_DIM / BM)     // 32
#define NWG (NBN * NBM)      // 2752, % 8 == 0
#define AQ (BM * BK)         // 8192 halves = 16 KiB per ring slot
#define BH (BN * 64)         // 8192 halves = 16 KiB per pair-half

// fallback (round-0 validated) kernel params
#define FBM 128
#define FBK 32
#define FASTRIDE 32
#define FBSTRIDE 40

typedef _Float16 half8   __attribute__((ext_vector_type(8)));
typedef _Float16 half2v  __attribute__((ext_vector_type(2)));
typedef float    floatx4 __attribute__((ext_vector_type(4)));

#define WS_NEEDED ((size_t)M_DIM * K_DIM * 2)   // 64 MiB: fp16 copy of x

__device__ __forceinline__ void async_lds16(const void* g, void* l) {
    __builtin_amdgcn_global_load_lds(
        (const __attribute__((address_space(1))) uint32_t*)g,
        (__attribute__((address_space(3))) uint32_t*)l, 16, 0, 0);
}

// ---------------- prepass: x fp32 -> fp16 (lossless; values are fp16-representable) ----
__global__ __launch_bounds__(256) void cvt_a(const float* __restrict__ x,
                                             _Float16* __restrict__ xh) {
    const size_t i = ((size_t)blockIdx.x * 256 + threadIdx.x) * 8;
    const float4 a = *(const float4*)(x + i);
    const float4 b = *(const float4*)(x + i + 4);
    half8 h;
    h[0] = (_Float16)a.x; h[1] = (_Float16)a.y; h[2] = (_Float16)a.z; h[3] = (_Float16)a.w;
    h[4] = (_Float16)b.x; h[5] = (_Float16)b.y; h[6] = (_Float16)b.z; h[7] = (_Float16)b.w;
    *(half8*)(xh + i) = h;
}

// ---------------- main GEMM: BK=32, 3-ring A, paired B dbuf, ONE barrier per slab ------
// Chain per slab is now just {barrier -> ds_read -> MFMA}: A-DMA has 2-slab cover so
// vmcnt(2/4) is pre-satisfied; B dequant runs AFTER the barrier overlapped with MFMA
// (writes the other pair-half); publish == protect (all ds-reads lgkm-drained at barrier).
// Footprint identical to r6: 80 KiB LDS, 2 blocks/CU, 16 waves, launch_bounds(512,4).
__global__ __launch_bounds__(512, 4) void ternary_gemm_r3(
    const _Float16* __restrict__ xh,   // (M, K) fp16
    const int*   __restrict__ pw,      // (K/16, N) packed 2-bit codes
    const float* __restrict__ scales,  // (K/128, N) fp32 holding fp16 values
    const float* __restrict__ bias,    // (N,) fp32 holding fp16 values
    float*       __restrict__ out)     // (M, N) fp32
{
    __shared__ __align__(16) _Float16 lds_a[3 * AQ];  // 48 KiB ring
    __shared__ __align__(16) _Float16 lds_b[2 * BH];  // 32 KiB pair-halves

    const int tid  = threadIdx.x;
    const int lane = tid & 63;
    const int w    = tid >> 6;

    // XCD-aware bijective swizzle; m-panel-major (FETCH 456->276MB, r5/r6-proven)
    const int bid = blockIdx.x;
    const int swz = (bid & 7) * (NWG / 8) + (bid >> 3);
    const int m0 = (swz / NBN) * BM;
    const int n0 = (swz % NBN) * BN;

    const int band = (w & 3) * 64;    // 8 waves = 4m x 2n; wave tile 64x64
    const int wn   = (w >> 2) * 64;

    // ---- A staging: 2 x 16B DMA per thread per slab; linear LDS dest ----
    // Slot (row, c) holds global chunk c ^ ((row>>1)&3): read pattern below is a
    // uniform 8-requests-per-bank b128 (the conflict-free floor, like r6's pattern).
    const _Float16* gaS[2];
    int laO[2];
    #pragma unroll
    for (int i = 0; i < 2; ++i) {
        const int idx = tid + i * 512;          // 0..1023
        const int row = idx >> 2;               // 0..255
        const int c   = idx & 3;                // 16B chunk of the 64B row
        gaS[i] = xh + (size_t)(m0 + row) * K_DIM + ((c ^ ((row >> 1) & 3)) * 8);
        laO[i] = idx * 8;
    }

    // ---- B staging (per 64-k PAIR, r6's exact proven layout/swizzle) ----
    const int nb = tid >> 2;                    // 0..127
    const int kp = tid & 3;                     // packed dword within the pair
    const int* pwp = pw + (size_t)kp * N_DIM + n0 + nb;
    const float* scp = scales + n0 + nb;
    const int s7 = nb & 7;
    const int cA = (kp * 2 + 0) ^ s7;
    const int cB = (kp * 2 + 1) ^ s7;

    floatx4 acc[4][4];
    #pragma unroll
    for (int i = 0; i < 4; ++i)
        #pragma unroll
        for (int j = 0; j < 4; ++j)
            acc[i][j] = floatx4{0.f, 0.f, 0.f, 0.f};

    const int lr = lane & 15;                   // row (A) / col (B,C) within 16-tile
    const int g  = lane >> 4;                   // k-quad
    const int x7 = lr & 7;

    int aoff[4], boff[4], bsl[2];
    #pragma unroll
    for (int t = 0; t < 4; ++t) {
        aoff[t] = (band + t * 16 + lr) * BK + ((g ^ ((lr >> 1) & 3)) * 8);  // complete
        boff[t] = (wn + t * 16 + lr) * 64;
    }
    bsl[0] = ((0 * 4 + g) ^ x7) * 8;            // within-pair half 0 / 1 chunk slot
    bsl[1] = ((1 * 4 + g) ^ x7) * 8;

    auto stage_a = [&](int t, int buf) {
        #pragma unroll
        for (int i = 0; i < 2; ++i)
            async_lds16(gaS[i] + t * BK, lds_a + buf * AQ + laO[i]);
    };
    // exact ternary dequant: 16 codes -> fp16 {-s, 0, +s} via v_perm byte templates
    auto stage_b = [&](uint32_t v, float scf, int half) {
        _Float16* rowb = lds_b + half * BH + nb * 64;
        _Float16 sh = (_Float16)scf;            // lossless (value is fp16)
        uint32_t sbits = (uint32_t)__builtin_bit_cast(unsigned short, sh);
        // template bytes: [0]=lo(s) [1]=hi(+s) [2]=0x00 [3]=hi(-s); s > 0
        uint32_t tmpl = sbits | (((sbits >> 8) ^ 0x80u) << 24);
        uint32_t q[8];
        #pragma unroll
        for (int j = 0; j < 8; ++j) {
            uint32_t t4 = (v >> (4 * j)) & 0xFu;             // c0 @bits1:0, c1 @bits3:2
            uint32_t sp = (t4 | (t4 << 14)) & 0x00030003u;   // c0 @byte0, c1 @byte2
            uint32_t sel = ((sp & 0x00010001u) << 1) | ((0x00030003u - sp) << 8);
            q[j] = __builtin_amdgcn_perm(tmpl, tmpl, sel);
        }
        *(uint4*)(rowb + cA * 8) = make_uint4(q[0], q[1], q[2], q[3]);
        *(uint4*)(rowb + cB * 8) = make_uint4(q[4], q[5], q[6], q[7]);
    };

    // ---- prologue: pv(pair0) + pv(pair1), A(0)->buf0, A(1)->buf1, B(pair0)->half0 ----
    uint32_t pvP1; float svP1;
    {
        uint32_t pv0 = (uint32_t)pwp[0];
        float    sv0 = scp[0];
        pvP1 = (uint32_t)pwp[(size_t)4 * N_DIM];   // pair 1 (issued BEFORE DMAs)
        svP1 = scp[0];                              // group of pair 1 == 0
        stage_a(0, 0);
        stage_a(1, 1);
        stage_b(pv0, sv0, 0);
    }
    uint32_t pvP2 = 0; float svP2 = 0.f;

    int rcur = 0, rstg = 2;   // t % 3, (t+2) % 3

    for (int t = 0; t < NSLAB; ++t) {
        // ---- single barrier per slab: publish A(t) (+ B pair when fresh), protect all ----
        // vmcnt drains own DMA(t) (2-slab cover -> pre-satisfied); counted so DMA(t+1)
        // and the in-flight pv loads are NOT drained (T4).
        if (t >= NSLAB - 2)      asm volatile("s_waitcnt vmcnt(0)" ::: "memory");
        else if ((t & 1) && t != NSLAB - 3)
                                 asm volatile("s_waitcnt vmcnt(4)" ::: "memory");
        else                     asm volatile("s_waitcnt vmcnt(2)" ::: "memory");
        asm volatile("s_waitcnt lgkmcnt(0)" ::: "memory");   // my ds ops all landed
        __builtin_amdgcn_sched_barrier(0);
        __builtin_amdgcn_s_barrier();
        __builtin_amdgcn_sched_barrier(0);

        // ---- issues (all off the next barrier's critical path) ----
        if (!(t & 1)) {                          // even slab: pair p = t>>1
            const int p = t >> 1;
            if (p + 2 < NPAIR) {                 // operand prefetch, 2 pairs ahead
                pvP2 = (uint32_t)pwp[(size_t)(p + 2) * 4 * N_DIM];
                svP2 = scp[(size_t)((p + 2) >> 1) * N_DIM];
            }
        }
        if (t + 2 < NSLAB) stage_a(t + 2, rstg); // 2 DMA into freed ring slot
        if (!(t & 1)) {
            const int p = t >> 1;
            if (p + 1 < NPAIR) stage_b(pvP1, svP1, (p + 1) & 1);  // overlapped w/ MFMA
        }

        // ---- compute slab t ----
        const _Float16* Ab = lds_a + rcur * AQ;
        const _Float16* Bb = lds_b + ((t >> 1) & 1) * BH;
        const int bs = bsl[t & 1];
        __builtin_amdgcn_s_setprio(1);
        half8 af[4], bf[4];
        #pragma unroll
        for (int tt = 0; tt < 4; ++tt) af[tt] = *(const half8*)&Ab[aoff[tt]];
        #pragma unroll
        for (int tt = 0; tt < 4; ++tt) bf[tt] = *(const half8*)&Bb[boff[tt] + bs];
        #pragma unroll
        for (int mt = 0; mt < 4; ++mt)
            #pragma unroll
            for (int nt = 0; nt < 4; ++nt)
                acc[mt][nt] = __builtin_amdgcn_mfma_f32_16x16x32_f16(
                    af[mt], bf[nt], acc[mt][nt], 0, 0, 0);
        __builtin_amdgcn_s_setprio(0);

        if (t & 1) { pvP1 = pvP2; svP1 = svP2; } // advance pair operand pipeline
        rcur = (rcur == 2) ? 0 : rcur + 1;
        rstg = (rstg == 2) ? 0 : rstg + 1;
    }

    // ---- epilogue: fp32 acc + fp32 bias, stored unrounded (validated numerics) ----
    float bv[4];
    #pragma unroll
    for (int nt = 0; nt < 4; ++nt) bv[nt] = bias[n0 + wn + nt * 16 + lr];

    const int rbase = g * 4;          // C layout: row = (lane>>4)*4 + reg
    #pragma unroll
    for (int mt = 0; mt < 4; ++mt) {
        #pragma unroll
        for (int nt = 0; nt < 4; ++nt) {
            const int col = n0 + wn + nt * 16 + lr;
            float* op = out + (size_t)(m0 + band + mt * 16 + rbase) * N_DIM + col;
            floatx4 a = acc[mt][nt];
            #pragma unroll
            for (int r = 0; r < 4; ++r)
                op[(size_t)r * N_DIM] = a[r] + bv[nt];
        }
    }
}

// ---------------- fallback: round-0 validated kernel (used if ws too small) ------------
__global__ __launch_bounds__(256, 2) void ternary_gemm(
    const float* __restrict__ x,
    const int*   __restrict__ pw,
    const float* __restrict__ scales,
    const float* __restrict__ bias,
    float*       __restrict__ out)
{
    __shared__ __align__(16) _Float16 lds_a[FBM * FASTRIDE];
    __shared__ __align__(16) _Float16 lds_b[FBM * FBSTRIDE];

    const int tid  = threadIdx.x;
    const int lane = tid & 63;
    const int wave = tid >> 6;

    const int n0 = blockIdx.x * FBM;
    const int m0 = blockIdx.y * FBM;

    const int wm = (wave & 1) * 64;
    const int wn = (wave >> 1) * 64;

    const int nb  = tid & 127;
    const int kpi = tid >> 7;
    const int*   pwp = pw + (size_t)kpi * N_DIM + n0 + nb;
    const float* scp = scales + n0 + nb;
    _Float16* bl = lds_b + nb * FBSTRIDE + kpi * 16;

    floatx4 acc[4][4];
    #pragma unroll
    for (int i = 0; i < 4; ++i)
        #pragma unroll
        for (int j = 0; j < 4; ++j)
            acc[i][j] = floatx4{0.f, 0.f, 0.f, 0.f};

    const int lr = lane & 15;
    const int qk = (lane >> 4) * 8;

    for (int slab = 0; slab < K_DIM / FBK; ++slab) {
        const int k0 = slab * FBK;

        #pragma unroll
        for (int i = 0; i < 4; ++i) {
            const int idx = tid + i * 256;
            const int row = idx >> 3;
            const int kq  = (idx & 7) * 4;
            float4 v4 = *(const float4*)(x + (size_t)(m0 + row) * K_DIM + k0 + kq);
            half2v h0; h0[0] = (_Float16)v4.x; h0[1] = (_Float16)v4.y;
            half2v h1; h1[0] = (_Float16)v4.z; h1[1] = (_Float16)v4.w;
            *(uint2*)(lds_a + row * FASTRIDE + kq) =
                make_uint2(__builtin_bit_cast(uint32_t, h0),
                           __builtin_bit_cast(uint32_t, h1));
        }

        uint32_t v  = (uint32_t)pwp[(size_t)slab * 2 * N_DIM];
        _Float16 sh = (_Float16)scp[(size_t)(slab >> 2) * N_DIM];
        uint32_t sbits = (uint32_t)__builtin_bit_cast(unsigned short, sh);
        uint32_t tmpl = sbits | (((sbits >> 8) ^ 0x80u) << 24);

        uint32_t q[8];
        #pragma unroll
        for (int j = 0; j < 8; ++j) {
            uint32_t t4 = (v >> (4 * j)) & 0xFu;
            uint32_t sp = (t4 | (t4 << 14)) & 0x00030003u;
            uint32_t sel = ((sp & 0x00010001u) << 1) | ((0x00030003u - sp) << 8);
            q[j] = __builtin_amdgcn_perm(tmpl, tmpl, sel);
        }
        *(uint4*)(bl)     = make_uint4(q[0], q[1], q[2], q[3]);
        *(uint4*)(bl + 8) = make_uint4(q[4], q[5], q[6], q[7]);

        __syncthreads();

        half8 af[4], bfr[4];
        #pragma unroll
        for (int t = 0; t < 4; ++t) {
            af[t]  = *(const half8*)&lds_a[(wm + t * 16 + lr) * FASTRIDE + qk];
            bfr[t] = *(const half8*)&lds_b[(wn + t * 16 + lr) * FBSTRIDE + qk];
        }
        #pragma unroll
        for (int mt = 0; mt < 4; ++mt)
            #pragma unroll
            for (int nt = 0; nt < 4; ++nt)
                acc[mt][nt] = __builtin_amdgcn_mfma_f32_16x16x32_f16(
                    af[mt], bfr[nt], acc[mt][nt], 0, 0, 0);

        __syncthreads();
    }

    float bv[4];
    #pragma unroll
    for (int nt = 0; nt < 4; ++nt) bv[nt] = bias[n0 + wn + nt * 16 + lr];

    const int rbase = (lane >> 4) * 4;
    #pragma unroll
    for (int mt = 0; mt < 4; ++mt) {
        #pragma unroll
        for (int nt = 0; nt < 4; ++nt) {
            const int col = n0 + wn + nt * 16 + lr;
            float* op = out + (size_t)(m0 + wm + mt * 16 + rbase) * N_DIM + col;
            floatx4 a = acc[mt][nt];
            #pragma unroll
            for (int r = 0; r < 4; ++r)
                op[(size_t)r * N_DIM] = a[r] + bv[nt];
        }
    }
}

extern "C" void kernel_launch(void* const* d_in, const int* in_sizes, int n_in,
                              void* d_out, int out_size, void* d_ws, size_t ws_size,
                              hipStream_t stream) {
    const float* x  = (const float*)d_in[0];
    const int*   pw = (const int*)d_in[1];
    const float* sc = (const float*)d_in[2];
    const float* bs = (const float*)d_in[3];
    float* out = (float*)d_out;

    if (d_ws != nullptr && ws_size >= WS_NEEDED) {
        _Float16* xh = (_Float16*)d_ws;
        cvt_a<<<dim3((unsigned)((size_t)M_DIM * K_DIM / (256 * 8))), 256, 0, stream>>>(x, xh);
        ternary_gemm_r3<<<dim3(NWG), 512, 0, stream>>>(xh, pw, sc, bs, out);
    } else {
        ternary_gemm<<<dim3(N_DIM / FBM, M_DIM / FBM), 256, 0, stream>>>(x, pw, sc, bs, out);
    }
}

// Round 10
// 1083.232 us; speedup vs baseline: 1.0700x; 1.0577x over previous
//
#include <hip/hip_runtime.h>
#include <stdint.h>

#define K_DIM 4096
#define N_DIM 11008
#define M_DIM 8192
#define BM 256
#define BN 128
#define BK 64
#define NSLAB (K_DIM / BK)   // 64
#define NBN (N_DIM / BN)     // 86
#define NBM (M_DIM / BM)     // 32
#define NWG (NBN * NBM)      // 2752, % 8 == 0
#define ABUF (BM * BK)       // 16384 halves = 32 KiB per A buffer

// fallback (round-0 validated) kernel params
#define FBM 128
#define FBK 32
#define FASTRIDE 32
#define FBSTRIDE 40

typedef _Float16 half8   __attribute__((ext_vector_type(8)));
typedef _Float16 half2v  __attribute__((ext_vector_type(2)));
typedef float    floatx4 __attribute__((ext_vector_type(4)));

#define WS_NEEDED ((size_t)M_DIM * K_DIM * 2)   // 64 MiB: fp16 copy of x

__device__ __forceinline__ void async_lds16(const void* g, void* l) {
    __builtin_amdgcn_global_load_lds(
        (const __attribute__((address_space(1))) uint32_t*)g,
        (__attribute__((address_space(3))) uint32_t*)l, 16, 0, 0);
}

// ---------------- prepass: x fp32 -> fp16 (lossless; values are fp16-representable) ----
__global__ __launch_bounds__(256) void cvt_a(const float* __restrict__ x,
                                             _Float16* __restrict__ xh) {
    const size_t i = ((size_t)blockIdx.x * 256 + threadIdx.x) * 8;
    const float4 a = *(const float4*)(x + i);
    const float4 b = *(const float4*)(x + i + 4);
    half8 h;
    h[0] = (_Float16)a.x; h[1] = (_Float16)a.y; h[2] = (_Float16)a.z; h[3] = (_Float16)a.w;
    h[4] = (_Float16)b.x; h[5] = (_Float16)b.y; h[6] = (_Float16)b.z; h[7] = (_Float16)b.w;
    *(half8*)(xh + i) = h;
}

// ---------------- main GEMM: r6 (session-best, 732 us): A double-buffer + counted vmcnt.
// LDS = 2x32K (A dbuf) + 16K (B, XOR-swizzled) = 80 KiB -> 2 blocks/CU at (512,4).
// Loop: issue DMA(t+1) -> other A buf FIRST, pv(t+2) prefetch, B(t) dequant+write,
// then vmcnt(6) (drains DMA(t) ONLY; DMA(t+1)+pv stay in flight), lgkm(0), s_barrier,
// MFMA (16x16x32, 4x4 per wave, setprio-wrapped), lgkm(0), s_barrier.
// DMA(t) latency is covered by the whole MFMA phase of t-1 instead of ~40 VALU ops.
__global__ __launch_bounds__(512, 4) void ternary_gemm_p2(
    const _Float16* __restrict__ xh,   // (M, K) fp16
    const int*   __restrict__ pw,      // (K/16, N) packed 2-bit codes
    const float* __restrict__ scales,  // (K/128, N) fp32 holding fp16 values
    const float* __restrict__ bias,    // (N,) fp32 holding fp16 values
    float*       __restrict__ out)     // (M, N) fp32
{
    __shared__ __align__(16) _Float16 lds_a[2 * ABUF];  // 64 KiB, linear dest (DMA)
    __shared__ __align__(16) _Float16 lds_b[BN * BK];   // 16 KiB, XOR-swizzled content

    const int tid  = threadIdx.x;
    const int lane = tid & 63;
    const int w    = tid >> 6;

    // XCD-aware bijective swizzle; m-panel-major within an XCD chunk (FETCH 456->276MB, r5)
    const int bid = blockIdx.x;
    const int swz = (bid & 7) * (NWG / 8) + (bid >> 3);
    const int m0 = (swz / NBN) * BM;
    const int n0 = (swz % NBN) * BN;

    const int band = (w & 3) * 64;    // 8 waves = 4m x 2n; wave tile 64x64
    const int wn   = (w >> 2) * 64;

    // ---- A staging: 4 x 16B DMA per thread; linear LDS dest, pre-swizzled source ----
    // LDS slot (row, c) holds global chunk c ^ (row & 7)  (zero-conflict pattern).
    const _Float16* ga[4];
    int laOff[4];
    #pragma unroll
    for (int i = 0; i < 4; ++i) {
        const int idx = tid + i * 512;          // 0..2047
        const int row = idx >> 3;               // 0..255
        const int c   = idx & 7;
        ga[i]    = xh + (size_t)(m0 + row) * K_DIM + ((c ^ (row & 7)) * 8);
        laOff[i] = idx * 8;
    }

    // ---- B staging: thread = (col nb, dword kp); 1 dword -> 2 swizzled 16B chunks ----
    const int nb = tid >> 2;                    // 0..127
    const int kp = tid & 3;                     // packed dword within slab
    const int* pwp = pw + (size_t)kp * N_DIM + n0 + nb;
    const float* scp = scales + n0 + nb;
    const int s7 = nb & 7;
    const int cA = (kp * 2 + 0) ^ s7;           // swizzled chunk slots
    const int cB = (kp * 2 + 1) ^ s7;
    _Float16* bl = lds_b + nb * BK;

    floatx4 acc[4][4];
    #pragma unroll
    for (int i = 0; i < 4; ++i)
        #pragma unroll
        for (int j = 0; j < 4; ++j)
            acc[i][j] = floatx4{0.f, 0.f, 0.f, 0.f};

    const int lr = lane & 15;                   // row (A) / col (B,C) within 16-tile
    const int g  = lane >> 4;                   // k-quad
    const int x7 = lr & 7;

    int aoff[4], boff[4];
    #pragma unroll
    for (int t = 0; t < 4; ++t) {
        aoff[t] = (band + t * 16 + lr) * BK;
        boff[t] = (wn   + t * 16 + lr) * BK;
    }

    auto stage_a = [&](int t, int buf) {
        #pragma unroll
        for (int i = 0; i < 4; ++i)
            async_lds16(ga[i] + t * BK, lds_a + buf * ABUF + laOff[i]);
    };
    // exact ternary dequant: 16 codes -> fp16 {-s, 0, +s} via v_perm byte templates
    auto stage_b = [&](uint32_t v, float scf) {
        _Float16 sh = (_Float16)scf;            // lossless (value is fp16)
        uint32_t sbits = (uint32_t)__builtin_bit_cast(unsigned short, sh);
        // template bytes: [0]=lo(s) [1]=hi(+s) [2]=0x00 [3]=hi(-s); s > 0
        uint32_t tmpl = sbits | (((sbits >> 8) ^ 0x80u) << 24);
        uint32_t q[8];
        #pragma unroll
        for (int j = 0; j < 8; ++j) {
            uint32_t t4 = (v >> (4 * j)) & 0xFu;             // c0 @bits1:0, c1 @bits3:2
            uint32_t sp = (t4 | (t4 << 14)) & 0x00030003u;   // c0 @byte0, c1 @byte2
            uint32_t sel = ((sp & 0x00010001u) << 1) | ((0x00030003u - sp) << 8);
            q[j] = __builtin_amdgcn_perm(tmpl, tmpl, sel);
        }
        *(uint4*)(bl + cA * 8) = make_uint4(q[0], q[1], q[2], q[3]);
        *(uint4*)(bl + cB * 8) = make_uint4(q[4], q[5], q[6], q[7]);
    };

    // ---- prologue: DMA slab 0 into buf0; pv(0), pv(1) loaded (blocking is fine) ----
    stage_a(0, 0);
    uint32_t pv0 = (uint32_t)pwp[0];
    float    sv0 = scp[0];
    uint32_t pv1 = (uint32_t)pwp[(size_t)4 * N_DIM];
    float    sv1 = scp[0];                      // group of slab 1 == 0

    for (int t = 0; t < NSLAB; ++t) {
        const int cur = t & 1;

        // (a) issue next slab's A-DMA into the other buffer (in flight through MFMA(t))
        if (t + 1 < NSLAB) stage_a(t + 1, cur ^ 1);
        // (b) prefetch slab t+2's packed dword + scale
        uint32_t pv2 = 0; float sv2 = 0.f;
        if (t + 2 < NSLAB) {
            pv2 = (uint32_t)pwp[(size_t)(t + 2) * 4 * N_DIM];
            sv2 = scp[(size_t)((t + 2) >> 1) * N_DIM];
        }
        // (c) B(t): dequant + swizzled ds_write (lds_b free since g-barrier(t-1))
        stage_b(pv0, sv0);

        // (d) drain DMA(t) only; DMA(t+1) [4] + pv2 [2] remain outstanding (T4)
        if (t + 2 < NSLAB)      asm volatile("s_waitcnt vmcnt(6)" ::: "memory");
        else if (t + 1 < NSLAB) asm volatile("s_waitcnt vmcnt(4)" ::: "memory");
        else                    asm volatile("s_waitcnt vmcnt(0)" ::: "memory");
        asm volatile("s_waitcnt lgkmcnt(0)" ::: "memory");   // my B writes landed
        __builtin_amdgcn_sched_barrier(0);
        __builtin_amdgcn_s_barrier();            // buf[cur] + lds_b published

        // (f) MFMA on buf[cur] + lds_b  (zero-conflict fragment pattern)
        const _Float16* Ab = lds_a + cur * ABUF;
        __builtin_amdgcn_s_setprio(1);
        #pragma unroll
        for (int h = 0; h < 2; ++h) {
            const int co = ((h * 4 + g) ^ x7) * 8;
            half8 af[4], bfr[4];
            #pragma unroll
            for (int tt = 0; tt < 4; ++tt) {
                af[tt]  = *(const half8*)&Ab[aoff[tt] + co];
                bfr[tt] = *(const half8*)&lds_b[boff[tt] + co];
            }
            #pragma unroll
            for (int mt = 0; mt < 4; ++mt)
                #pragma unroll
                for (int nt = 0; nt < 4; ++nt)
                    acc[mt][nt] = __builtin_amdgcn_mfma_f32_16x16x32_f16(
                        af[mt], bfr[nt], acc[mt][nt], 0, 0, 0);
        }
        __builtin_amdgcn_s_setprio(0);

        // (g) my ds reads complete -> safe for next iter's B overwrite after barrier
        asm volatile("s_waitcnt lgkmcnt(0)" ::: "memory");
        __builtin_amdgcn_sched_barrier(0);
        __builtin_amdgcn_s_barrier();

        pv0 = pv1; sv0 = sv1; pv1 = pv2; sv1 = sv2;
    }

    // ---- epilogue: fp32 acc + fp32 bias, stored unrounded (validated numerics) ----
    float bv[4];
    #pragma unroll
    for (int nt = 0; nt < 4; ++nt) bv[nt] = bias[n0 + wn + nt * 16 + lr];

    const int rbase = g * 4;          // C layout: row = (lane>>4)*4 + reg
    #pragma unroll
    for (int mt = 0; mt < 4; ++mt) {
        #pragma unroll
        for (int nt = 0; nt < 4; ++nt) {
            const int col = n0 + wn + nt * 16 + lr;
            float* op = out + (size_t)(m0 + band + mt * 16 + rbase) * N_DIM + col;
            floatx4 a = acc[mt][nt];
            #pragma unroll
            for (int r = 0; r < 4; ++r)
                op[(size_t)r * N_DIM] = a[r] + bv[nt];
        }
    }
}

// ---------------- fallback: round-0 validated kernel (used if ws too small) ------------
__global__ __launch_bounds__(256, 2) void ternary_gemm(
    const float* __restrict__ x,
    const int*   __restrict__ pw,
    const float* __restrict__ scales,
    const float* __restrict__ bias,
    float*       __restrict__ out)
{
    __shared__ __align__(16) _Float16 lds_a[FBM * FASTRIDE];
    __shared__ __align__(16) _Float16 lds_b[FBM * FBSTRIDE];

    const int tid  = threadIdx.x;
    const int lane = tid & 63;
    const int wave = tid >> 6;

    const int n0 = blockIdx.x * FBM;
    const int m0 = blockIdx.y * FBM;

    const int wm = (wave & 1) * 64;
    const int wn = (wave >> 1) * 64;

    const int nb  = tid & 127;
    const int kpi = tid >> 7;
    const int*   pwp = pw + (size_t)kpi * N_DIM + n0 + nb;
    const float* scp = scales + n0 + nb;
    _Float16* bl = lds_b + nb * FBSTRIDE + kpi * 16;

    floatx4 acc[4][4];
    #pragma unroll
    for (int i = 0; i < 4; ++i)
        #pragma unroll
        for (int j = 0; j < 4; ++j)
            acc[i][j] = floatx4{0.f, 0.f, 0.f, 0.f};

    const int lr = lane & 15;
    const int qk = (lane >> 4) * 8;

    for (int slab = 0; slab < K_DIM / FBK; ++slab) {
        const int k0 = slab * FBK;

        #pragma unroll
        for (int i = 0; i < 4; ++i) {
            const int idx = tid + i * 256;
            const int row = idx >> 3;
            const int kq  = (idx & 7) * 4;
            float4 v4 = *(const float4*)(x + (size_t)(m0 + row) * K_DIM + k0 + kq);
            half2v h0; h0[0] = (_Float16)v4.x; h0[1] = (_Float16)v4.y;
            half2v h1; h1[0] = (_Float16)v4.z; h1[1] = (_Float16)v4.w;
            *(uint2*)(lds_a + row * FASTRIDE + kq) =
                make_uint2(__builtin_bit_cast(uint32_t, h0),
                           __builtin_bit_cast(uint32_t, h1));
        }

        uint32_t v  = (uint32_t)pwp[(size_t)slab * 2 * N_DIM];
        _Float16 sh = (_Float16)scp[(size_t)(slab >> 2) * N_DIM];
        uint32_t sbits = (uint32_t)__builtin_bit_cast(unsigned short, sh);
        uint32_t tmpl = sbits | (((sbits >> 8) ^ 0x80u) << 24);

        uint32_t q[8];
        #pragma unroll
        for (int j = 0; j < 8; ++j) {
            uint32_t t4 = (v >> (4 * j)) & 0xFu;
            uint32_t sp = (t4 | (t4 << 14)) & 0x00030003u;
            uint32_t sel = ((sp & 0x00010001u) << 1) | ((0x00030003u - sp) << 8);
            q[j] = __builtin_amdgcn_perm(tmpl, tmpl, sel);
        }
        *(uint4*)(bl)     = make_uint4(q[0], q[1], q[2], q[3]);
        *(uint4*)(bl + 8) = make_uint4(q[4], q[5], q[6], q[7]);

        __syncthreads();

        half8 af[4], bfr[4];
        #pragma unroll
        for (int t = 0; t < 4; ++t) {
            af[t]  = *(const half8*)&lds_a[(wm + t * 16 + lr) * FASTRIDE + qk];
            bfr[t] = *(const half8*)&lds_b[(wn + t * 16 + lr) * FBSTRIDE + qk];
        }
        #pragma unroll
        for (int mt = 0; mt < 4; ++mt)
            #pragma unroll
            for (int nt = 0; nt < 4; ++nt)
                acc[mt][nt] = __builtin_amdgcn_mfma_f32_16x16x32_f16(
                    af[mt], bfr[nt], acc[mt][nt], 0, 0, 0);

        __syncthreads();
    }

    float bv[4];
    #pragma unroll
    for (int nt = 0; nt < 4; ++nt) bv[nt] = bias[n0 + wn + nt * 16 + lr];

    const int rbase = (lane >> 4) * 4;
    #pragma unroll
    for (int mt = 0; mt < 4; ++mt) {
        #pragma unroll
        for (int nt = 0; nt < 4; ++nt) {
            const int col = n0 + wn + nt * 16 + lr;
            float* op = out + (size_t)(m0 + wm + mt * 16 + rbase) * N_DIM + col;
            floatx4 a = acc[mt][nt];
            #pragma unroll
            for (int r = 0; r < 4; ++r)
                op[(size_t)r * N_DIM] = a[r] + bv[nt];
        }
    }
}

extern "C" void kernel_launch(void* const* d_in, const int* in_sizes, int n_in,
                              void* d_out, int out_size, void* d_ws, size_t ws_size,
                              hipStream_t stream) {
    const float* x  = (const float*)d_in[0];
    const int*   pw = (const int*)d_in[1];
    const float* sc = (const float*)d_in[2];
    const float* bs = (const float*)d_in[3];
    float* out = (float*)d_out;

    if (d_ws != nullptr && ws_size >= WS_NEEDED) {
        _Float16* xh = (_Float16*)d_ws;
        cvt_a<<<dim3((unsigned)((size_t)M_DIM * K_DIM / (256 * 8))), 256, 0, stream>>>(x, xh);
        ternary_gemm_p2<<<dim3(NWG), 512, 0, stream>>>(xh, pw, sc, bs, out);
    } else {
        ternary_gemm<<<dim3(N_DIM / FBM, M_DIM / FBM), 256, 0, stream>>>(x, pw, sc, bs, out);
    }
}